// Round 9
// baseline (5867.872 us; speedup 1.0000x reference)
//
#include <hip/hip_runtime.h>
#include <cstdint>
#include <cstddef>

// SNN pipeline, round 18:
//  k1: unchanged from round 10.
//  k2: HYBRID staging. r9-r17 invariant (dur x MfmaUtil == ~1325 us, util
//      53-59%) finally explained: the shared LDS pipe was the limiter —
//      per block-tile: 48 b128 reads (576cyc) + 16KB DMA (128cyc) = 704 cyc
//      vs 388 cyc MFMA across the 4 SIMD pipes -> 388/704 = 55% = measured.
//      Fix: A fragments are wave-private -> load straight to named cur/nxt
//      REGISTERS (2 i32x4/tile, small enough to stay resident — r17's 12
//      named i32x4 overflowed the allocator and serialized); bytes proven
//      identical to the old AL slots. B (shared by all 4 strips, L2-hot)
//      stays LDS-staged: 1 gl_lds16 per wave per tile (8 slots <-> 8 waves).
//      New LDS budget: 8x4 b128 reads (384) + 8KB DMA (64) = 448 cyc vs
//      MFMA 388 -> ceiling ~87%. vmcnt(0)+barrier per tile kept (A-prefetch
//      drain is covered by the ~1300cyc compute phase; correctness-first vs
//      counted-vmcnt games). MFMA stream bit-identical -> absmax 0.0234375.
//      Ballot epilogue unchanged (r16).
//  k3: unchanged (mask->wo dot, ascending cols).
// ws: w2d 4MiB @0 | s1bits 128MiB @16MiB | po32 masks 80MiB @160MiB

typedef _Float16 f16;
typedef _Float16 f16x8 __attribute__((ext_vector_type(8)));
typedef float f32x4 __attribute__((ext_vector_type(4)));
typedef int i32x4 __attribute__((ext_vector_type(4)));
typedef unsigned int u32;

#define MFMA16(A, B, C) __builtin_amdgcn_mfma_f32_16x16x32_f16(A, B, C, 0, 0, 0)

static constexpr int BSZ = 65536;
static constexpr int IN = 512;
static constexpr int H = 1024;

__device__ __forceinline__ void gl_lds16(const void* g, void* l) {
    __builtin_amdgcn_global_load_lds(
        (const __attribute__((address_space(1))) u32*)g,
        (__attribute__((address_space(3))) u32*)l, 16, 0, 0);
}

// W2[k][j] fp32 -> w2d[plane][j][k] f16 Dekker limbs: plane0 = f16(w),
// plane1 = f16((w - hi) * 2^11).
__global__ void prep_dekker(const float* __restrict__ src, f16* __restrict__ dst) {
    int idx = blockIdx.x * 256 + threadIdx.x;
    int k = idx >> 10;
    int j = idx & 1023;
    float w = src[(size_t)k * 1024 + j];
    f16 hi = (f16)w;
    float lo = (w - (float)hi) * 2048.0f;
    size_t o = (size_t)j * 1024 + k;
    dst[o] = hi;
    dst[o + (size_t)H * H] = (f16)lo;
}

// k1: fp32 k-ordered FMA-chain GEMM (BLAS-replica) + fp32-replica LIF -> masks.
// tile 128 b-rows x 256 h-cols, 256 threads = 16 ht x 16 bt, thread = 8b x 16h.
__global__ __launch_bounds__(256, 2) void k1_chain(
    const float* __restrict__ x, const float* __restrict__ w1,
    const float* __restrict__ b1, unsigned short* __restrict__ s1b) {
    __shared__ float xs[32][132];   // [k][b]; stride 132: rows 16B-aligned, banks spread
    __shared__ float ws[32][256];   // [k][h]
    const int hblk = blockIdx.x;    // 4
    const int bblk = blockIdx.y;    // 512
    const int tid = threadIdx.x;
    const int ht = tid & 15, bt = tid >> 4;
    const int h0 = hblk * 256, b0 = bblk * 128;

    float acc[8][16] = {};

    float4 xv[4], wv[8];
#pragma unroll
    for (int i = 0; i < 4; ++i) {
        int idx = tid + 256 * i;            // 1024 f4: 128 rows x 8 segs
        int br = idx >> 3, ks = idx & 7;
        xv[i] = *(const float4*)&x[(size_t)(b0 + br) * IN + ks * 4];
    }
#pragma unroll
    for (int i = 0; i < 8; ++i) {
        int idx = tid + 256 * i;            // 2048 f4: 32 rows x 64 segs
        int kr = idx >> 6, c4 = idx & 63;
        wv[i] = *(const float4*)&w1[(size_t)kr * H + h0 + c4 * 4];
    }

    for (int kc = 0; kc < 512; kc += 32) {
        __syncthreads();                    // prev compute's LDS reads done
#pragma unroll
        for (int i = 0; i < 4; ++i) {
            int idx = tid + 256 * i;
            int br = idx >> 3, ks = idx & 7;
            xs[ks * 4 + 0][br] = xv[i].x;
            xs[ks * 4 + 1][br] = xv[i].y;
            xs[ks * 4 + 2][br] = xv[i].z;
            xs[ks * 4 + 3][br] = xv[i].w;
        }
#pragma unroll
        for (int i = 0; i < 8; ++i) {
            int idx = tid + 256 * i;
            int kr = idx >> 6, c4 = idx & 63;
            *(float4*)&ws[kr][c4 * 4] = wv[i];
        }
        __syncthreads();
        int kn = (kc + 32) & 511;           // wraps to 0 on last chunk (dummy)
#pragma unroll
        for (int i = 0; i < 4; ++i) {
            int idx = tid + 256 * i;
            int br = idx >> 3, ks = idx & 7;
            xv[i] = *(const float4*)&x[(size_t)(b0 + br) * IN + kn + ks * 4];
        }
#pragma unroll
        for (int i = 0; i < 8; ++i) {
            int idx = tid + 256 * i;
            int kr = idx >> 6, c4 = idx & 63;
            wv[i] = *(const float4*)&w1[(size_t)(kn + kr) * H + h0 + c4 * 4];
        }
#pragma unroll 2
        for (int k = 0; k < 32; ++k) {
            float xr[8];
            *(float4*)&xr[0] = *(const float4*)&xs[k][bt * 8];
            *(float4*)&xr[4] = *(const float4*)&xs[k][bt * 8 + 4];
            float wr[16];
#pragma unroll
            for (int g = 0; g < 4; ++g)
                *(float4*)&wr[g * 4] = *(const float4*)&ws[k][ht * 4 + 64 * g];
#pragma unroll
            for (int i = 0; i < 8; ++i)
#pragma unroll
                for (int j = 0; j < 16; ++j)
                    acc[i][j] = fmaf(xr[i], wr[j], acc[i][j]);  // strict k-order chain
        }
    }

    float b1v[16];
#pragma unroll
    for (int g = 0; g < 4; ++g)
#pragma unroll
        for (int m = 0; m < 4; ++m)
            b1v[g * 4 + m] = b1[h0 + g * 64 + ht * 4 + m];
#pragma unroll
    for (int i = 0; i < 8; ++i) {
        unsigned short outb[16];
#pragma unroll
        for (int j = 0; j < 16; ++j) {
            float c = __fadd_rn(acc[i][j], b1v[j]);
            float m = 0.0f;
            unsigned bits = 0u;
#pragma unroll
            for (int t = 0; t < 10; ++t) {
                float rst = (m > 1.0f) ? 1.0f : 0.0f;
                m = __fmul_rn(0.9f, m);
                m = __fadd_rn(m, c);
                m = __fsub_rn(m, rst);
                if (m > 1.0f) bits |= (1u << t);
            }
            outb[j] = (unsigned short)bits;
        }
        size_t row = (size_t)(b0 + bt * 8 + i);
#pragma unroll
        for (int g = 0; g < 4; ++g)
            *(int2*)&s1b[row * H + h0 + g * 64 + ht * 4] = ((const int2*)outb)[g];
    }
}

// k2: spike GEMM, hybrid staging. Block = 64 rows x 32 cols, 512 threads =
// 8 waves: wave = (strip = w&3) x (colfrag = w>>2); each wave owns all 10
// timesteps of its 16 rows x 16 cols. A: global->named regs (wave-private).
// B: LDS-staged, 1 gl_lds16 per wave per tile, fragment-linear slots.
__global__ __launch_bounds__(512, 4) void k2_spikes_gemm(
    const unsigned short* __restrict__ s1bits, const f16* __restrict__ w2d,
    const float* __restrict__ b2, u32* __restrict__ po32) {
    __shared__ i32x4 BL[2][2][2][2][64];   // [buf][kch][plane][cf][slot] 16 KB

    const int jblk = blockIdx.x, bblk = blockIdx.y;
    const int tid = threadIdx.x;
    const int lane = tid & 63, wave = tid >> 6;
    const int strip = wave & 3, cfw = wave >> 2;   // compute roles
    const int l15 = lane & 15, loct = lane >> 4;

    // B staging role: wave w owns slot (kch=w&1, plane=(w>>1)&1, cf=w>>2);
    // LDS dest = wave-uniform base + lane*16 == gl_lds semantics; bytes per
    // slot identical to r16's two-per-wave staging.
    const int skch = wave & 1, spl = (wave >> 1) & 1, scf = wave >> 2;
    const f16* gBs = w2d + (size_t)spl * H * H
                   + (size_t)(jblk * 32 + scf * 16 + l15) * 1024 + loct * 8 + skch * 32;
    // A source (wave-private; bytes identical to the old AL slots).
    const unsigned short* gA =
        s1bits + (size_t)(bblk * 64 + strip * 16 + l15) * 1024 + loct * 8;

    f32x4 acc[10][2] = {};   // [tt][plane] = 80 acc regs

    typedef union { i32x4 i; unsigned long long u[2]; f16x8 h; } U;

#define STAGE_B(t_)                                                      \
    do {                                                                 \
        int bi_ = (t_) & 1;                                              \
        int kk_ = ((t_) * 64) & 1023;                                    \
        gl_lds16(gBs + kk_, &BL[bi_][skch][spl][scf][0]);                \
    } while (0)

    // prologue: stage B(0), load A(0), drain, release
    STAGE_B(0);
    i32x4 a0c = *(const i32x4*)(gA);        // kch0
    i32x4 a1c = *(const i32x4*)(gA + 32);   // kch1
    asm volatile("s_waitcnt vmcnt(0)" ::: "memory");
    __builtin_amdgcn_s_barrier();

#pragma unroll 2
    for (int t = 0; t < 16; ++t) {
        const int bi = t & 1;
        STAGE_B(t + 1);                      // dummy wrap at t=15
        const int kn = ((t + 1) * 64) & 1023;
        i32x4 a0n = *(const i32x4*)(gA + kn);        // A prefetch, named regs
        i32x4 a1n = *(const i32x4*)(gA + kn + 32);
#pragma unroll
        for (int kch = 0; kch < 2; ++kch) {
            U m;
            m.i = kch ? a1c : a0c;
            U p0; p0.i = BL[bi][kch][0][cfw][lane];
            U p1; p1.i = BL[bi][kch][1][cfw][lane];
            f16x8 bf0 = p0.h, bf1 = p1.h;
            __builtin_amdgcn_s_setprio(1);
#pragma unroll
            for (int tt = 0; tt < 10; ++tt) {
                const int sh = 10 - tt;
                U r;
                r.u[0] = (m.u[0] << sh) & 0x0400040004000400ULL;
                r.u[1] = (m.u[1] << sh) & 0x0400040004000400ULL;
                acc[tt][0] = MFMA16(r.h, bf0, acc[tt][0]);
                acc[tt][1] = MFMA16(r.h, bf1, acc[tt][1]);
            }
            __builtin_amdgcn_s_setprio(0);
        }
        // drain B-DMA (and the A prefetch — compute phase ~1300cyc covered
        // its ~900cyc latency), then release buf^1 to all waves.
        asm volatile("s_waitcnt vmcnt(0)" ::: "memory");
        __builtin_amdgcn_s_barrier();
        a0c = a0n; a1c = a1n;
    }
#undef STAGE_B

    // epilogue: Dekker combine in f64 (guards near-threshold spikes),
    // fp32-replica LIF-2 (ops bit-identical), then __ballot -> u16
    // col-spike-mask per (tt, row). po32 word [jblk][tt][row]: lo u16 = cfw0
    // cols, hi u16 = cfw1 cols. Each halfword written exactly once.
    int col0 = jblk * 32 + cfw * 16 + l15;
    float b2v = b2[col0];
    float m2[4] = {0.0f, 0.0f, 0.0f, 0.0f};
    unsigned short* pw = (unsigned short*)po32;

#pragma unroll
    for (int tt = 0; tt < 10; ++tt) {
#pragma unroll
        for (int r = 0; r < 4; ++r) {
            float iv = (float)((double)acc[tt][0][r] * 16384.0 + (double)acc[tt][1][r] * 8.0);
            iv = __fadd_rn(iv, b2v);
            float rst = (m2[r] > 1.0f) ? 1.0f : 0.0f;
            m2[r] = __fmul_rn(0.9f, m2[r]);
            m2[r] = __fadd_rn(m2[r], iv);
            m2[r] = __fsub_rn(m2[r], rst);
            unsigned long long bal = __ballot(m2[r] > 1.0f);
            if (l15 == r) {
                int row = bblk * 64 + strip * 16 + loct * 4 + r;
                pw[(((size_t)jblk * 10 + tt) * BSZ + row) * 2 + cfw] =
                    (unsigned short)(bal >> (loct * 16));
            }
        }
    }
}

// k3: mask->wo dot in ascending column order + fp32-replica LIF-out, mean.
// Per b-row: 320 coalesced u32 mask loads; per mask 32 predicated f32 adds
// with the wo 32-chunk held in registers (staged via LDS broadcast).
__global__ __launch_bounds__(256) void k3_out(
    const u32* __restrict__ po32, const float* __restrict__ wo,
    const float* __restrict__ bo, float* __restrict__ out) {
    __shared__ float wos[1024];
    const int tid = threadIdx.x;
    for (int i = tid; i < 1024; i += 256) wos[i] = wo[i];
    __syncthreads();
    const int b = blockIdx.x * 256 + tid;

    float inp[10] = {};
    for (int jb = 0; jb < 32; ++jb) {
        float wr[32];
#pragma unroll
        for (int g = 0; g < 8; ++g)
            *(float4*)&wr[g * 4] = *(const float4*)&wos[jb * 32 + g * 4];
#pragma unroll
        for (int t = 0; t < 10; ++t) {
            u32 mk = po32[((size_t)jb * 10 + t) * BSZ + b];
#pragma unroll
            for (int bit = 0; bit < 32; ++bit)
                inp[t] += ((mk >> bit) & 1u) ? wr[bit] : 0.0f;
        }
    }

    float bov = bo[0];
    float mo = 0.0f, s = 0.0f;
#pragma unroll
    for (int t = 0; t < 10; ++t) {
        float iv = __fadd_rn(inp[t], bov);
        float rst = (mo > 1.0f) ? 1.0f : 0.0f;
        mo = __fmul_rn(0.9f, mo);
        mo = __fadd_rn(mo, iv);
        mo = __fsub_rn(mo, rst);
        s += mo;
    }
    out[b] = s / 10.0f;
}

extern "C" void kernel_launch(void* const* d_in, const int* in_sizes, int n_in,
                              void* d_out, int out_size, void* d_ws, size_t ws_size,
                              hipStream_t stream) {
    (void)in_sizes; (void)n_in; (void)out_size; (void)ws_size;
    const float* x  = (const float*)d_in[0];
    const float* W1 = (const float*)d_in[1];
    const float* b1 = (const float*)d_in[2];
    const float* W2 = (const float*)d_in[3];
    const float* b2 = (const float*)d_in[4];
    const float* Wo = (const float*)d_in[5];
    const float* bo = (const float*)d_in[6];
    float* out = (float*)d_out;

    char* ws = (char*)d_ws;
    f16* w2d = (f16*)ws;                                                   // 4 MiB @ 0
    unsigned short* s1bits = (unsigned short*)(ws + ((size_t)16 << 20));   // 128 MiB
    u32* po32 = (u32*)(ws + ((size_t)160 << 20));                          // 80 MiB

    prep_dekker<<<dim3((H * H) / 256), 256, 0, stream>>>(W2, w2d);
    k1_chain<<<dim3(4, BSZ / 128), 256, 0, stream>>>(x, W1, b1, s1bits);
    k2_spikes_gemm<<<dim3(H / 32, BSZ / 64), 512, 0, stream>>>(s1bits, w2d, b2, po32);
    k3_out<<<dim3(BSZ / 256), 256, 0, stream>>>(po32, Wo, bo, out);
}